// Round 9
// baseline (285.421 us; speedup 1.0000x reference)
//
#include <hip/hip_runtime.h>
#include <cstdint>

// Problem constants (match reference)
#define N_PTS 100000
#define DIN   40
#define DH    30
#define DOUT  10
#define NB    10000
#define NNB   64
#define NR    10
#define EPSF  1e-5f

// v_rcp_f32 + one Newton step: ~fp32-exact. Used on GJ pivots (R6: raw rcp
// amplified absmax 0.031->0.25; Newton costs 2 VALU x 64 steps).
__device__ __forceinline__ float rcp_nr(float x) {
    float r = __builtin_amdgcn_rcpf(x);
    return r * (2.0f - x * r);
}

// Raw v_sqrt_f32 (no libm fixup; args in [0, ~200]).
__device__ __forceinline__ float fast_sqrt(float x) {
    return __builtin_amdgcn_sqrtf(x);
}

// Broadcast lane LANE's value via v_readlane_b32 -> SGPR (VALU pipe, not the
// per-CU DS crossbar: R3 lesson). SGPR result feeds FMA directly.
//
// ALLOCATOR MODEL (R4-R8): the arch-VGPR allotment tracks the min-waves
// occupancy floor of __launch_bounds__ -- cap 512 -> 128 arch (clean, R3);
// cap 256 -> 52 arch; cap 170 -> 80; cap 128 -> 60. Whatever doesn't fit
// arch is parked in AGPR-spill space, and since v_readlane cannot read an
// AGPR, every broadcast of an AGPR-resident element pays v_accvgpr_read:
// ~15.5k instrs/wave measured vs ~8k source. ONLY (64,1) allocates the
// arrays fully in arch VGPRs. Occupancy then follows ACTUAL usage
// (512/~128 = 4 waves/SIMD), not the floor promise.
__device__ __forceinline__ float lane_bcast(float x, int lane) {
    return __int_as_float(__builtin_amdgcn_readlane(__float_as_int(x), lane));
}

// ---------------------------------------------------------------------------
// Kernel 1: MLP embedding. One point per thread; weights staged in LDS.
// ---------------------------------------------------------------------------
__global__ __launch_bounds__(256) void mlp_kernel(
    const float* __restrict__ x,
    const float* __restrict__ W1, const float* __restrict__ b1, const float* __restrict__ a1p,
    const float* __restrict__ W2, const float* __restrict__ b2, const float* __restrict__ a2p,
    float* __restrict__ emb)
{
    __shared__ float sW1[DH * DIN];
    __shared__ float sW2[DOUT * DH];
    __shared__ float sb1[DH];
    __shared__ float sb2[DOUT];
    for (int i = threadIdx.x; i < DH * DIN; i += 256) sW1[i] = W1[i];
    for (int i = threadIdx.x; i < DOUT * DH; i += 256) sW2[i] = W2[i];
    if (threadIdx.x < DH)   sb1[threadIdx.x] = b1[threadIdx.x];
    if (threadIdx.x < DOUT) sb2[threadIdx.x] = b2[threadIdx.x];
    const float a1 = a1p[0], a2 = a2p[0];
    __syncthreads();

    const int n = blockIdx.x * 256 + threadIdx.x;
    if (n >= N_PTS) return;

    float xv[DIN];
    const float4* xp = reinterpret_cast<const float4*>(x + (size_t)n * DIN); // 160B rows
#pragma unroll
    for (int q = 0; q < DIN / 4; ++q) {
        float4 v = xp[q];
        xv[4*q+0] = v.x; xv[4*q+1] = v.y; xv[4*q+2] = v.z; xv[4*q+3] = v.w;
    }

    float h[DH];
#pragma unroll
    for (int i = 0; i < DH; ++i) {
        float acc = sb1[i];
#pragma unroll
        for (int j = 0; j < DIN; ++j) acc = fmaf(xv[j], sW1[i * DIN + j], acc);
        h[i] = acc > 0.0f ? acc : a1 * acc;
    }

    float* eo = emb + (size_t)n * DOUT;
#pragma unroll
    for (int d = 0; d < DOUT; ++d) {
        float acc = sb2[d];
#pragma unroll
        for (int i = 0; i < DH; ++i) acc = fmaf(h[i], sW2[d * DH + i], acc);
        eo[d] = acc > 0.0f ? acc : a2 * acc;
    }
}

// ---------------------------------------------------------------------------
// Template-recursive solve blocks: every array index AND readlane lane index
// is a compile-time constant (R2: runtime k -> scratch; R3: __shfl -> DS).
// Gauss-Jordan: step K eliminates column K from all rows but K; after 64
// steps A is diagonal, x_i = rr_i / diag_i.
// ---------------------------------------------------------------------------

// Build row `lane` of Kplus = exp(-dist) + eps*I
template<int J>
struct Build {
    static __device__ __forceinline__ void run(float (&ar)[NNB], const float (&xn)[DOUT],
                                               const float sq, const int lane) {
        float dj = 0.0f;
#pragma unroll
        for (int d = 0; d < DOUT; ++d) dj = fmaf(lane_bcast(xn[d], J), xn[d], dj);
        const float sqj = lane_bcast(sq, J);
        const float d2  = sq + sqj - 2.0f * dj;
        const float kij = __expf(-fast_sqrt(fmaxf(d2, 0.0f)));
        ar[J] = (J == lane) ? (1.0f + EPSF) : kij;   // exact diag + jitter
        Build<J + 1>::run(ar, xn, sq, lane);
    }
};
template<>
struct Build<NNB> {
    static __device__ __forceinline__ void run(float (&)[NNB], const float (&)[DOUT],
                                               float, int) {}
};

// Gauss-Jordan step K
template<int K>
struct GJ {
    static __device__ __forceinline__ void run(float (&ar)[NNB], float (&rr)[NR + 1],
                                               float& mydiag, const int lane) {
        const float pd  = lane_bcast(ar[K], K);   // pivot diag (SGPR)
        const float inv = rcp_nr(pd);
        const float m   = (lane == K) ? 0.0f : ar[K] * inv;
        mydiag = (lane == K) ? ar[K] : mydiag;    // column K never touched again
#pragma unroll
        for (int j = K + 1; j < NNB; ++j)
            ar[j] = fmaf(-m, lane_bcast(ar[j], K), ar[j]);
#pragma unroll
        for (int r = 0; r <= NR; ++r)
            rr[r] = fmaf(-m, lane_bcast(rr[r], K), rr[r]);
        GJ<K + 1>::run(ar, rr, mydiag, lane);
    }
};
template<>
struct GJ<NNB> {
    static __device__ __forceinline__ void run(float (&)[NNB], float (&)[NR + 1],
                                               float&, int) {}
};

// ---------------------------------------------------------------------------
// Kernel 2: ONE WAVE PER BLOCK (64 threads), one batch item per wave.
// __launch_bounds__(64, 1): the ONLY config (R3) where the allocator puts
// the full ~110-float live set in arch VGPRs -- no AGPR split, no
// accvgpr_read on the broadcast path. Residency follows actual usage:
// ~128 VGPR -> 4 waves/SIMD.
// ---------------------------------------------------------------------------
__global__ __launch_bounds__(64, 1) void solve_kernel(
    const float* __restrict__ emb,
    const int* __restrict__ bidx,
    const int* __restrict__ bnn,
    const float* __restrict__ tnn_g,
    float* __restrict__ pred,   // [NB][NR]
    float* __restrict__ var,    // [NB]
    float* __restrict__ part)   // [NB][NR] sigma_sq partials
{
    const int lane = threadIdx.x;   // 0..63
    const int b    = blockIdx.x;

    // Gather this lane's neighbor embedding (10 floats, 8B-aligned rows)
    const int idx = bnn[b * NNB + lane];
    float xn[DOUT];
    {
        const float2* ep = reinterpret_cast<const float2*>(emb + (size_t)idx * DOUT);
#pragma unroll
        for (int q = 0; q < DOUT / 2; ++q) { float2 v = ep[q]; xn[2*q] = v.x; xn[2*q+1] = v.y; }
    }
    // Center embedding (same for all lanes; broadcast through cache)
    const int bi = bidx[b];
    float sq = 0.0f, dotb = 0.0f, sqb = 0.0f;
#pragma unroll
    for (int d = 0; d < DOUT; ++d) {
        const float xbd = emb[(size_t)bi * DOUT + d];
        sq   = fmaf(xn[d], xn[d], sq);
        dotb = fmaf(xbd, xn[d], dotb);
        sqb  = fmaf(xbd, xbd, sqb);
    }
    const float d2c = sqb + sq - 2.0f * dotb;
    const float kc  = __expf(-fast_sqrt(fmaxf(d2c, 0.0f)));

    // Targets: load once, keep live (loose cap allows it)
    float tn[NR];
    {
        const float2* tp = reinterpret_cast<const float2*>(
            tnn_g + (size_t)b * NNB * NR + (size_t)lane * NR);
#pragma unroll
        for (int q = 0; q < NR / 2; ++q) { float2 v = tp[q]; tn[2*q] = v.x; tn[2*q+1] = v.y; }
    }

    // K matrix row (registers, static indices only)
    float ar[NNB];
    Build<0>::run(ar, xn, sq, lane);

    // RHS row: [targets(10), Kcross]
    float rr[NR + 1];
#pragma unroll
    for (int r = 0; r < NR; ++r) rr[r] = tn[r];
    rr[NR] = kc;

    float mydiag = 1.0f;
    GJ<0>::run(ar, rr, mydiag, lane);
    const float dinv = rcp_nr(mydiag);   // x_i = rr_i * dinv (A now diagonal)

    // Outputs: predictions, variance, sigma_sq partials (wave butterfly reduce)
    float pv[NR], sg[NR];
#pragma unroll
    for (int r = 0; r < NR; ++r) {
        const float xr = rr[r] * dinv;     // coeffs[lane][r]
        pv[r] = kc * xr;
        sg[r] = tn[r] * xr;
    }
    float vv = kc * rr[NR] * dinv;         // kc * kc_solve[lane]
#pragma unroll
    for (int off = 32; off > 0; off >>= 1) {
#pragma unroll
        for (int r = 0; r < NR; ++r) {
            pv[r] += __shfl_xor(pv[r], off);
            sg[r] += __shfl_xor(sg[r], off);
        }
        vv += __shfl_xor(vv, off);
    }
    if (lane == 0) {
#pragma unroll
        for (int r = 0; r < NR; ++r) {
            pred[b * NR + r] = pv[r];
            part[b * NR + r] = sg[r];
        }
        var[b] = 1.0f - vv;
    }
}

// ---------------------------------------------------------------------------
// Kernel 3: deterministic reduction of sigma_sq partials (fixed order)
// ---------------------------------------------------------------------------
__global__ __launch_bounds__(256) void reduce_kernel(
    const float* __restrict__ part, float* __restrict__ sig)
{
    float acc[NR];
#pragma unroll
    for (int r = 0; r < NR; ++r) acc[r] = 0.0f;
    for (int b = threadIdx.x; b < NB; b += 256) {
#pragma unroll
        for (int r = 0; r < NR; ++r) acc[r] += part[b * NR + r];
    }
#pragma unroll
    for (int off = 32; off > 0; off >>= 1) {
#pragma unroll
        for (int r = 0; r < NR; ++r) acc[r] += __shfl_xor(acc[r], off);
    }
    __shared__ float s[4][NR];
    const int w = threadIdx.x >> 6, l = threadIdx.x & 63;
    if (l == 0) {
#pragma unroll
        for (int r = 0; r < NR; ++r) s[w][r] = acc[r];
    }
    __syncthreads();
    if (threadIdx.x == 0) {
        const float scale = 1.0f / ((float)NB * (float)NNB);
#pragma unroll
        for (int r = 0; r < NR; ++r)
            sig[r] = (s[0][r] + s[1][r] + s[2][r] + s[3][r]) * scale;
    }
}

// ---------------------------------------------------------------------------
extern "C" void kernel_launch(void* const* d_in, const int* in_sizes, int n_in,
                              void* d_out, int out_size, void* d_ws, size_t ws_size,
                              hipStream_t stream)
{
    const float* x    = (const float*)d_in[0];
    const int*   bidx = (const int*)  d_in[1];
    const int*   bnn  = (const int*)  d_in[2];
    // d_in[3] = batch_targets: unused by the reference computation
    const float* tnn  = (const float*)d_in[4];
    const float* W1   = (const float*)d_in[5];
    const float* b1   = (const float*)d_in[6];
    const float* a1   = (const float*)d_in[7];
    const float* W2   = (const float*)d_in[8];
    const float* b2   = (const float*)d_in[9];
    const float* a2   = (const float*)d_in[10];

    float* out  = (float*)d_out;
    float* pred = out;                 // 100000
    float* var  = out + NB * NR;       // 10000
    float* sig  = out + NB * NR + NB;  // 10

    float* emb  = (float*)d_ws;        // N_PTS*DOUT floats (4 MB)
    float* part = emb + (size_t)N_PTS * DOUT; // NB*NR floats (400 KB)

    mlp_kernel<<<(N_PTS + 255) / 256, 256, 0, stream>>>(x, W1, b1, a1, W2, b2, a2, emb);
    solve_kernel<<<NB, 64, 0, stream>>>(emb, bidx, bnn, tnn, pred, var, part);
    reduce_kernel<<<1, 256, 0, stream>>>(part, sig);
}

// Round 10
// 231.392 us; speedup vs baseline: 1.2335x; 1.2335x over previous
//
#include <hip/hip_runtime.h>
#include <cstdint>

// Problem constants (match reference)
#define N_PTS 100000
#define DIN   40
#define DH    30
#define DOUT  10
#define NB    10000
#define NNB   64
#define NR    10
#define EPSF  1e-5f

// v_rcp_f32 + one Newton step: ~fp32-exact (R6: raw rcp on pivots -> 8x
// worse absmax).
__device__ __forceinline__ float rcp_nr(float x) {
    float r = __builtin_amdgcn_rcpf(x);
    return r * (2.0f - x * r);
}

// Raw v_sqrt_f32 (no libm fixup; args in [0, ~200]).
__device__ __forceinline__ float fast_sqrt(float x) {
    return __builtin_amdgcn_sqrtf(x);
}

// Broadcast lane LANE's value via v_readlane_b32 -> SGPR (VALU pipe, not the
// per-CU DS crossbar: R3 lesson).
// R9 lesson: the 215-280us basin across ALL launch-bounds configs + VALUBusy
// stuck ~50-60% at any occupancy = per-wave stalls, not allocation. The
// per-step serial chain readlane->rcp->newton->mul (~30cy) gates ~150
// update instrs; R10 pipelines the next pivot chain under this step's
// updates.
__device__ __forceinline__ float lane_bcast(float x, int lane) {
    return __int_as_float(__builtin_amdgcn_readlane(__float_as_int(x), lane));
}

// ---------------------------------------------------------------------------
// Kernel 1: MLP embedding. One point per thread; weights staged in LDS.
// ---------------------------------------------------------------------------
__global__ __launch_bounds__(256) void mlp_kernel(
    const float* __restrict__ x,
    const float* __restrict__ W1, const float* __restrict__ b1, const float* __restrict__ a1p,
    const float* __restrict__ W2, const float* __restrict__ b2, const float* __restrict__ a2p,
    float* __restrict__ emb)
{
    __shared__ float sW1[DH * DIN];
    __shared__ float sW2[DOUT * DH];
    __shared__ float sb1[DH];
    __shared__ float sb2[DOUT];
    for (int i = threadIdx.x; i < DH * DIN; i += 256) sW1[i] = W1[i];
    for (int i = threadIdx.x; i < DOUT * DH; i += 256) sW2[i] = W2[i];
    if (threadIdx.x < DH)   sb1[threadIdx.x] = b1[threadIdx.x];
    if (threadIdx.x < DOUT) sb2[threadIdx.x] = b2[threadIdx.x];
    const float a1 = a1p[0], a2 = a2p[0];
    __syncthreads();

    const int n = blockIdx.x * 256 + threadIdx.x;
    if (n >= N_PTS) return;

    float xv[DIN];
    const float4* xp = reinterpret_cast<const float4*>(x + (size_t)n * DIN); // 160B rows
#pragma unroll
    for (int q = 0; q < DIN / 4; ++q) {
        float4 v = xp[q];
        xv[4*q+0] = v.x; xv[4*q+1] = v.y; xv[4*q+2] = v.z; xv[4*q+3] = v.w;
    }

    float h[DH];
#pragma unroll
    for (int i = 0; i < DH; ++i) {
        float acc = sb1[i];
#pragma unroll
        for (int j = 0; j < DIN; ++j) acc = fmaf(xv[j], sW1[i * DIN + j], acc);
        h[i] = acc > 0.0f ? acc : a1 * acc;
    }

    float* eo = emb + (size_t)n * DOUT;
#pragma unroll
    for (int d = 0; d < DOUT; ++d) {
        float acc = sb2[d];
#pragma unroll
        for (int i = 0; i < DH; ++i) acc = fmaf(h[i], sW2[d * DH + i], acc);
        eo[d] = acc > 0.0f ? acc : a2 * acc;
    }
}

// ---------------------------------------------------------------------------
// Template-recursive solve blocks: every array index AND readlane lane index
// is a compile-time constant (R2: runtime k -> scratch; R3: __shfl -> DS).
// ---------------------------------------------------------------------------

// Build row `lane` of Kplus = exp(-dist) + eps*I
template<int J>
struct Build {
    static __device__ __forceinline__ void run(float (&ar)[NNB], const float (&xn)[DOUT],
                                               const float sq, const int lane) {
        float dj = 0.0f;
#pragma unroll
        for (int d = 0; d < DOUT; ++d) dj = fmaf(lane_bcast(xn[d], J), xn[d], dj);
        const float sqj = lane_bcast(sq, J);
        const float d2  = sq + sqj - 2.0f * dj;
        const float kij = __expf(-fast_sqrt(fmaxf(d2, 0.0f)));
        ar[J] = (J == lane) ? (1.0f + EPSF) : kij;   // exact diag + jitter
        Build<J + 1>::run(ar, xn, sq, lane);
    }
};
template<>
struct Build<NNB> {
    static __device__ __forceinline__ void run(float (&)[NNB], const float (&)[DOUT],
                                               float, int) {}
};

// Software-pipelined Gauss-Jordan step K. `inv` (= 1/pivot_K) arrives as a
// parameter, computed DURING step K-1's updates. Step K: (1) compute m,
// (2) update column K+1 immediately, (3) LAUNCH step K+1's pivot chain
// (readlane + rcp_nr) so its ~30cy latency hides under (4) the remaining
// ~140 column/RHS update instructions.
template<int K>
struct GJ {
    static __device__ __forceinline__ void run(float (&ar)[NNB], float (&rr)[NR + 1],
                                               float& mydiag, const int lane,
                                               const float inv) {
        const float m = (lane == K) ? 0.0f : ar[K] * inv;
        mydiag = (lane == K) ? ar[K] : mydiag;    // column K never touched again

        // (2) column K+1 first (pivot row value read from lane K pre-update)
        ar[K + 1] = fmaf(-m, lane_bcast(ar[K + 1], K), ar[K + 1]);
        // (3) next pivot chain: lane K+1's ar[K+1] is now final
        const float inv_next = rcp_nr(lane_bcast(ar[K + 1], K + 1));

        // (4) bulk updates overlap inv_next's latency
#pragma unroll
        for (int j = K + 2; j < NNB; ++j)
            ar[j] = fmaf(-m, lane_bcast(ar[j], K), ar[j]);
#pragma unroll
        for (int r = 0; r <= NR; ++r)
            rr[r] = fmaf(-m, lane_bcast(rr[r], K), rr[r]);

        GJ<K + 1>::run(ar, rr, mydiag, lane, inv_next);
    }
};
// Last step: only the RHS remains.
template<>
struct GJ<NNB - 1> {
    static __device__ __forceinline__ void run(float (&ar)[NNB], float (&rr)[NR + 1],
                                               float& mydiag, const int lane,
                                               const float inv) {
        constexpr int K = NNB - 1;
        const float m = (lane == K) ? 0.0f : ar[K] * inv;
        mydiag = (lane == K) ? ar[K] : mydiag;
#pragma unroll
        for (int r = 0; r <= NR; ++r)
            rr[r] = fmaf(-m, lane_bcast(rr[r], K), rr[r]);
    }
};

// ---------------------------------------------------------------------------
// Kernel 2: one wave per batch item, 2 items per 128-thread block.
// (128, 4): empirically the best basin config (R7: 16 waves/CU). R10 adds
// the pipelined pivot chain to lift per-wave issue efficiency.
// ---------------------------------------------------------------------------
__global__ __launch_bounds__(128, 4) void solve_kernel(
    const float* __restrict__ emb,
    const int* __restrict__ bidx,
    const int* __restrict__ bnn,
    const float* __restrict__ tnn_g,
    float* __restrict__ pred,   // [NB][NR]
    float* __restrict__ var,    // [NB]
    float* __restrict__ part)   // [NB][NR] sigma_sq partials
{
    const int wave = threadIdx.x >> 6;        // 0..1
    const int lane = threadIdx.x & 63;
    const int b    = blockIdx.x * 2 + wave;   // NB = 5000*2, exact

    // Gather this lane's neighbor embedding (10 floats, 8B-aligned rows)
    const int idx = bnn[b * NNB + lane];
    float xn[DOUT];
    {
        const float2* ep = reinterpret_cast<const float2*>(emb + (size_t)idx * DOUT);
#pragma unroll
        for (int q = 0; q < DOUT / 2; ++q) { float2 v = ep[q]; xn[2*q] = v.x; xn[2*q+1] = v.y; }
    }
    // Center embedding (same for all lanes; broadcast through cache)
    const int bi = bidx[b];
    float sq = 0.0f, dotb = 0.0f, sqb = 0.0f;
#pragma unroll
    for (int d = 0; d < DOUT; ++d) {
        const float xbd = emb[(size_t)bi * DOUT + d];
        sq   = fmaf(xn[d], xn[d], sq);
        dotb = fmaf(xbd, xn[d], dotb);
        sqb  = fmaf(xbd, xbd, sqb);
    }
    const float d2c = sqb + sq - 2.0f * dotb;
    const float kc  = __expf(-fast_sqrt(fmaxf(d2c, 0.0f)));

    // K matrix row (registers, static indices only)
    float ar[NNB];
    Build<0>::run(ar, xn, sq, lane);

    // RHS row: [targets(10), Kcross]. tn reloaded at the end (pressure).
    float rr[NR + 1];
    {
        const float2* tp = reinterpret_cast<const float2*>(
            tnn_g + (size_t)b * NNB * NR + (size_t)lane * NR);
#pragma unroll
        for (int q = 0; q < NR / 2; ++q) { float2 v = tp[q]; rr[2*q] = v.x; rr[2*q+1] = v.y; }
    }
    rr[NR] = kc;

    // Prologue of the pipeline: step-0 pivot chain
    const float inv0 = rcp_nr(lane_bcast(ar[0], 0));
    float mydiag = 1.0f;
    GJ<0>::run(ar, rr, mydiag, lane, inv0);
    const float dinv = rcp_nr(mydiag);   // x_i = rr_i * dinv (A now diagonal)

    // Reload targets for sigma_sq partials
    float tn[NR];
    {
        const float2* tp = reinterpret_cast<const float2*>(
            tnn_g + (size_t)b * NNB * NR + (size_t)lane * NR);
#pragma unroll
        for (int q = 0; q < NR / 2; ++q) { float2 v = tp[q]; tn[2*q] = v.x; tn[2*q+1] = v.y; }
    }

    // Outputs: predictions, variance, sigma_sq partials (wave butterfly reduce)
    float pv[NR], sg[NR];
#pragma unroll
    for (int r = 0; r < NR; ++r) {
        const float xr = rr[r] * dinv;     // coeffs[lane][r]
        pv[r] = kc * xr;
        sg[r] = tn[r] * xr;
    }
    float vv = kc * rr[NR] * dinv;         // kc * kc_solve[lane]
#pragma unroll
    for (int off = 32; off > 0; off >>= 1) {
#pragma unroll
        for (int r = 0; r < NR; ++r) {
            pv[r] += __shfl_xor(pv[r], off);
            sg[r] += __shfl_xor(sg[r], off);
        }
        vv += __shfl_xor(vv, off);
    }
    if (lane == 0) {
#pragma unroll
        for (int r = 0; r < NR; ++r) {
            pred[b * NR + r] = pv[r];
            part[b * NR + r] = sg[r];
        }
        var[b] = 1.0f - vv;
    }
}

// ---------------------------------------------------------------------------
// Kernel 3: deterministic reduction of sigma_sq partials (fixed order)
// ---------------------------------------------------------------------------
__global__ __launch_bounds__(256) void reduce_kernel(
    const float* __restrict__ part, float* __restrict__ sig)
{
    float acc[NR];
#pragma unroll
    for (int r = 0; r < NR; ++r) acc[r] = 0.0f;
    for (int b = threadIdx.x; b < NB; b += 256) {
#pragma unroll
        for (int r = 0; r < NR; ++r) acc[r] += part[b * NR + r];
    }
#pragma unroll
    for (int off = 32; off > 0; off >>= 1) {
#pragma unroll
        for (int r = 0; r < NR; ++r) acc[r] += __shfl_xor(acc[r], off);
    }
    __shared__ float s[4][NR];
    const int w = threadIdx.x >> 6, l = threadIdx.x & 63;
    if (l == 0) {
#pragma unroll
        for (int r = 0; r < NR; ++r) s[w][r] = acc[r];
    }
    __syncthreads();
    if (threadIdx.x == 0) {
        const float scale = 1.0f / ((float)NB * (float)NNB);
#pragma unroll
        for (int r = 0; r < NR; ++r)
            sig[r] = (s[0][r] + s[1][r] + s[2][r] + s[3][r]) * scale;
    }
}

// ---------------------------------------------------------------------------
extern "C" void kernel_launch(void* const* d_in, const int* in_sizes, int n_in,
                              void* d_out, int out_size, void* d_ws, size_t ws_size,
                              hipStream_t stream)
{
    const float* x    = (const float*)d_in[0];
    const int*   bidx = (const int*)  d_in[1];
    const int*   bnn  = (const int*)  d_in[2];
    // d_in[3] = batch_targets: unused by the reference computation
    const float* tnn  = (const float*)d_in[4];
    const float* W1   = (const float*)d_in[5];
    const float* b1   = (const float*)d_in[6];
    const float* a1   = (const float*)d_in[7];
    const float* W2   = (const float*)d_in[8];
    const float* b2   = (const float*)d_in[9];
    const float* a2   = (const float*)d_in[10];

    float* out  = (float*)d_out;
    float* pred = out;                 // 100000
    float* var  = out + NB * NR;       // 10000
    float* sig  = out + NB * NR + NB;  // 10

    float* emb  = (float*)d_ws;        // N_PTS*DOUT floats (4 MB)
    float* part = emb + (size_t)N_PTS * DOUT; // NB*NR floats (400 KB)

    mlp_kernel<<<(N_PTS + 255) / 256, 256, 0, stream>>>(x, W1, b1, a1, W2, b2, a2, emb);
    solve_kernel<<<NB / 2, 128, 0, stream>>>(emb, bidx, bnn, tnn, pred, var, part);
    reduce_kernel<<<1, 256, 0, stream>>>(part, sig);
}

// Round 13
// 199.155 us; speedup vs baseline: 1.4332x; 1.1619x over previous
//
#include <hip/hip_runtime.h>
#include <cstdint>

// Problem constants (match reference)
#define N_PTS 100000
#define DIN   40
#define DH    30
#define DOUT  10
#define NB    10000
#define NNB   64
#define NR    10
#define EPSF  1e-5f

// v_rcp_f32 + one Newton step: ~fp32-exact (R6: raw rcp on pivots -> 8x
// worse absmax).
__device__ __forceinline__ float rcp_nr(float x) {
    float r = __builtin_amdgcn_rcpf(x);
    return r * (2.0f - x * r);
}

// Raw v_sqrt_f32 (no libm fixup; args in [0, ~200]).
__device__ __forceinline__ float fast_sqrt(float x) {
    return __builtin_amdgcn_sqrtf(x);
}

// Broadcast lane LANE's value via v_readlane_b32 -> SGPR (VALU pipe, not the
// per-CU DS crossbar: R3 lesson).
//
// NUMERICS INVARIANT (R12 lesson -- DO NOT BREAK): ~200 of the 10k batches
// contain exactly-duplicated neighbor indices. For those, the kernel-matrix
// entry must be exp(-sqrt(0)) = 1 EXACTLY, which requires dj (dot chain)
// to be BITWISE EQUAL to sq (norm chain) for identical vectors -> both must
// be a single sequential fma chain over d=0..9. R12 split dj into 2
// accumulators: d2 became ~1e-6 instead of 0, sqrt's infinite slope at 0
// turned that into kij~0.9986, the antisym eigenvalue went 1e-5 -> 1e-3,
// coeffs shrank ~100x vs reference -> sigma_sq absmax 12.25. R11's
// symmetry-sourcing broke the same knife edge via asymmetric update
// rounding. Elimination ORDER of independent elements is free; the BUILD
// arithmetic per element is not.
__device__ __forceinline__ float lane_bcast(float x, int lane) {
    return __int_as_float(__builtin_amdgcn_readlane(__float_as_int(x), lane));
}

// ---------------------------------------------------------------------------
// Kernel 1: MLP embedding. One point per thread; weights staged in LDS.
// ---------------------------------------------------------------------------
__global__ __launch_bounds__(256) void mlp_kernel(
    const float* __restrict__ x,
    const float* __restrict__ W1, const float* __restrict__ b1, const float* __restrict__ a1p,
    const float* __restrict__ W2, const float* __restrict__ b2, const float* __restrict__ a2p,
    float* __restrict__ emb)
{
    __shared__ float sW1[DH * DIN];
    __shared__ float sW2[DOUT * DH];
    __shared__ float sb1[DH];
    __shared__ float sb2[DOUT];
    for (int i = threadIdx.x; i < DH * DIN; i += 256) sW1[i] = W1[i];
    for (int i = threadIdx.x; i < DOUT * DH; i += 256) sW2[i] = W2[i];
    if (threadIdx.x < DH)   sb1[threadIdx.x] = b1[threadIdx.x];
    if (threadIdx.x < DOUT) sb2[threadIdx.x] = b2[threadIdx.x];
    const float a1 = a1p[0], a2 = a2p[0];
    __syncthreads();

    const int n = blockIdx.x * 256 + threadIdx.x;
    if (n >= N_PTS) return;

    float xv[DIN];
    const float4* xp = reinterpret_cast<const float4*>(x + (size_t)n * DIN); // 160B rows
#pragma unroll
    for (int q = 0; q < DIN / 4; ++q) {
        float4 v = xp[q];
        xv[4*q+0] = v.x; xv[4*q+1] = v.y; xv[4*q+2] = v.z; xv[4*q+3] = v.w;
    }

    float h[DH];
#pragma unroll
    for (int i = 0; i < DH; ++i) {
        float acc = sb1[i];
#pragma unroll
        for (int j = 0; j < DIN; ++j) acc = fmaf(xv[j], sW1[i * DIN + j], acc);
        h[i] = acc > 0.0f ? acc : a1 * acc;
    }

    float* eo = emb + (size_t)n * DOUT;
#pragma unroll
    for (int d = 0; d < DOUT; ++d) {
        float acc = sb2[d];
#pragma unroll
        for (int i = 0; i < DH; ++i) acc = fmaf(h[i], sW2[d * DH + i], acc);
        eo[d] = acc > 0.0f ? acc : a2 * acc;
    }
}

// ---------------------------------------------------------------------------
// Template-recursive solve blocks: every array index AND readlane lane index
// is a compile-time constant (R2: runtime k -> scratch; R3: __shfl -> DS).
// ---------------------------------------------------------------------------

// Build row `lane` of Kplus = exp(-dist) + eps*I.
// Readlanes batched (free reorder); dj is a SINGLE sequential fma chain,
// bitwise-identical to the sq chain for duplicated neighbors (see invariant).
template<int J>
struct Build {
    static __device__ __forceinline__ void run(float (&ar)[NNB], const float (&xn)[DOUT],
                                               const float sq, const int lane) {
        float px[DOUT];
#pragma unroll
        for (int d = 0; d < DOUT; ++d) px[d] = lane_bcast(xn[d], J);
        float dj = 0.0f;
#pragma unroll
        for (int d = 0; d < DOUT; ++d) dj = fmaf(px[d], xn[d], dj);
        const float sqj = lane_bcast(sq, J);
        const float d2  = sq + sqj - 2.0f * dj;
        const float kij = __expf(-fast_sqrt(fmaxf(d2, 0.0f)));
        ar[J] = (J == lane) ? (1.0f + EPSF) : kij;   // exact diag + jitter
        Build<J + 1>::run(ar, xn, sq, lane);
    }
};
template<>
struct Build<NNB> {
    static __device__ __forceinline__ void run(float (&)[NNB], const float (&)[DOUT],
                                               float, int) {}
};

// Batched rank-1 update group: CNT elements starting at J. Issues CNT
// independent readlanes (SGPR temps), then CNT fmas. Per-element arithmetic
// identical to R10; only issue order differs (ILP: readlane latency
// amortized CNT-wide instead of exposed per element).
template<int K, int J, int CNT>
struct Grp {
    static __device__ __forceinline__ void run(float (&ar)[NNB], const float m) {
        float p[CNT];
#pragma unroll
        for (int t = 0; t < CNT; ++t) p[t] = lane_bcast(ar[J + t], K);
#pragma unroll
        for (int t = 0; t < CNT; ++t) ar[J + t] = fmaf(-m, p[t], ar[J + t]);
    }
};

// Drive groups of 8 over the suffix [J, NNB)
template<int K, int J>
struct Suffix {
    static __device__ __forceinline__ void run(float (&ar)[NNB], const float m) {
        constexpr int REM = NNB - J;
        constexpr int CNT = (REM < 8) ? REM : 8;
        Grp<K, J, CNT>::run(ar, m);
        if constexpr (J + CNT < NNB) Suffix<K, J + CNT>::run(ar, m);
    }
};

// Software-pipelined Gauss-Jordan step K (R10 semantics exactly). `inv`
// (= 1/pivot_K) arrives as a parameter, computed during step K-1's updates.
template<int K>
struct GJ {
    static __device__ __forceinline__ void run(float (&ar)[NNB], float (&rr)[NR + 1],
                                               float& mydiag, const int lane,
                                               const float inv) {
        const float m = (lane == K) ? 0.0f : ar[K] * inv;
        mydiag = (lane == K) ? ar[K] : mydiag;    // column K never touched again

        // Column K+1 first (pivot-row value from lane K, pre-update)
        ar[K + 1] = fmaf(-m, lane_bcast(ar[K + 1], K), ar[K + 1]);
        // Next pivot chain launches early: lane K+1's ar[K+1] is now final
        const float inv_next = rcp_nr(lane_bcast(ar[K + 1], K + 1));

        // Bulk updates, batched 8-wide; overlap inv_next's latency
        if constexpr (K + 2 < NNB) Suffix<K, K + 2>::run(ar, m);

        // RHS: all 11 readlanes, then all 11 fmas
        {
            float pr[NR + 1];
#pragma unroll
            for (int r = 0; r <= NR; ++r) pr[r] = lane_bcast(rr[r], K);
#pragma unroll
            for (int r = 0; r <= NR; ++r) rr[r] = fmaf(-m, pr[r], rr[r]);
        }

        GJ<K + 1>::run(ar, rr, mydiag, lane, inv_next);
    }
};
// Last step: only the RHS remains.
template<>
struct GJ<NNB - 1> {
    static __device__ __forceinline__ void run(float (&ar)[NNB], float (&rr)[NR + 1],
                                               float& mydiag, const int lane,
                                               const float inv) {
        constexpr int K = NNB - 1;
        const float m = (lane == K) ? 0.0f : ar[K] * inv;
        mydiag = (lane == K) ? ar[K] : mydiag;
        float pr[NR + 1];
#pragma unroll
        for (int r = 0; r <= NR; ++r) pr[r] = lane_bcast(rr[r], K);
#pragma unroll
        for (int r = 0; r <= NR; ++r) rr[r] = fmaf(-m, pr[r], rr[r]);
    }
};

// ---------------------------------------------------------------------------
// Kernel 2: one wave per batch item, 2 items per 128-thread block.
// (128, 4): R10's measured config -- only delta vs R10 is readlane batching.
// ---------------------------------------------------------------------------
__global__ __launch_bounds__(128, 4) void solve_kernel(
    const float* __restrict__ emb,
    const int* __restrict__ bidx,
    const int* __restrict__ bnn,
    const float* __restrict__ tnn_g,
    float* __restrict__ pred,   // [NB][NR]
    float* __restrict__ var,    // [NB]
    float* __restrict__ part)   // [NB][NR] sigma_sq partials
{
    const int wave = threadIdx.x >> 6;        // 0..1
    const int lane = threadIdx.x & 63;
    const int b    = blockIdx.x * 2 + wave;   // NB = 5000*2, exact

    // Gather this lane's neighbor embedding (10 floats, 8B-aligned rows)
    const int idx = bnn[b * NNB + lane];
    float xn[DOUT];
    {
        const float2* ep = reinterpret_cast<const float2*>(emb + (size_t)idx * DOUT);
#pragma unroll
        for (int q = 0; q < DOUT / 2; ++q) { float2 v = ep[q]; xn[2*q] = v.x; xn[2*q+1] = v.y; }
    }
    // Center embedding (same for all lanes; broadcast through cache)
    const int bi = bidx[b];
    float sq = 0.0f, dotb = 0.0f, sqb = 0.0f;
#pragma unroll
    for (int d = 0; d < DOUT; ++d) {
        const float xbd = emb[(size_t)bi * DOUT + d];
        sq   = fmaf(xn[d], xn[d], sq);
        dotb = fmaf(xbd, xn[d], dotb);
        sqb  = fmaf(xbd, xbd, sqb);
    }
    const float d2c = sqb + sq - 2.0f * dotb;
    const float kc  = __expf(-fast_sqrt(fmaxf(d2c, 0.0f)));

    // K matrix row (registers, static indices only)
    float ar[NNB];
    Build<0>::run(ar, xn, sq, lane);

    // RHS row: [targets(10), Kcross]. tn reloaded at the end (pressure).
    float rr[NR + 1];
    {
        const float2* tp = reinterpret_cast<const float2*>(
            tnn_g + (size_t)b * NNB * NR + (size_t)lane * NR);
#pragma unroll
        for (int q = 0; q < NR / 2; ++q) { float2 v = tp[q]; rr[2*q] = v.x; rr[2*q+1] = v.y; }
    }
    rr[NR] = kc;

    // Prologue of the pipeline: step-0 pivot chain
    const float inv0 = rcp_nr(lane_bcast(ar[0], 0));
    float mydiag = 1.0f;
    GJ<0>::run(ar, rr, mydiag, lane, inv0);
    const float dinv = rcp_nr(mydiag);   // x_i = rr_i * dinv (A now diagonal)

    // Reload targets for sigma_sq partials
    float tn[NR];
    {
        const float2* tp = reinterpret_cast<const float2*>(
            tnn_g + (size_t)b * NNB * NR + (size_t)lane * NR);
#pragma unroll
        for (int q = 0; q < NR / 2; ++q) { float2 v = tp[q]; tn[2*q] = v.x; tn[2*q+1] = v.y; }
    }

    // Outputs: predictions, variance, sigma_sq partials (wave butterfly reduce)
    float pv[NR], sg[NR];
#pragma unroll
    for (int r = 0; r < NR; ++r) {
        const float xr = rr[r] * dinv;     // coeffs[lane][r]
        pv[r] = kc * xr;
        sg[r] = tn[r] * xr;
    }
    float vv = kc * rr[NR] * dinv;         // kc * kc_solve[lane]
#pragma unroll
    for (int off = 32; off > 0; off >>= 1) {
#pragma unroll
        for (int r = 0; r < NR; ++r) {
            pv[r] += __shfl_xor(pv[r], off);
            sg[r] += __shfl_xor(sg[r], off);
        }
        vv += __shfl_xor(vv, off);
    }
    if (lane == 0) {
#pragma unroll
        for (int r = 0; r < NR; ++r) {
            pred[b * NR + r] = pv[r];
            part[b * NR + r] = sg[r];
        }
        var[b] = 1.0f - vv;
    }
}

// ---------------------------------------------------------------------------
// Kernel 3: deterministic reduction of sigma_sq partials (fixed order)
// ---------------------------------------------------------------------------
__global__ __launch_bounds__(256) void reduce_kernel(
    const float* __restrict__ part, float* __restrict__ sig)
{
    float acc[NR];
#pragma unroll
    for (int r = 0; r < NR; ++r) acc[r] = 0.0f;
    for (int b = threadIdx.x; b < NB; b += 256) {
#pragma unroll
        for (int r = 0; r < NR; ++r) acc[r] += part[b * NR + r];
    }
#pragma unroll
    for (int off = 32; off > 0; off >>= 1) {
#pragma unroll
        for (int r = 0; r < NR; ++r) acc[r] += __shfl_xor(acc[r], off);
    }
    __shared__ float s[4][NR];
    const int w = threadIdx.x >> 6, l = threadIdx.x & 63;
    if (l == 0) {
#pragma unroll
        for (int r = 0; r < NR; ++r) s[w][r] = acc[r];
    }
    __syncthreads();
    if (threadIdx.x == 0) {
        const float scale = 1.0f / ((float)NB * (float)NNB);
#pragma unroll
        for (int r = 0; r < NR; ++r)
            sig[r] = (s[0][r] + s[1][r] + s[2][r] + s[3][r]) * scale;
    }
}

// ---------------------------------------------------------------------------
extern "C" void kernel_launch(void* const* d_in, const int* in_sizes, int n_in,
                              void* d_out, int out_size, void* d_ws, size_t ws_size,
                              hipStream_t stream)
{
    const float* x    = (const float*)d_in[0];
    const int*   bidx = (const int*)  d_in[1];
    const int*   bnn  = (const int*)  d_in[2];
    // d_in[3] = batch_targets: unused by the reference computation
    const float* tnn  = (const float*)d_in[4];
    const float* W1   = (const float*)d_in[5];
    const float* b1   = (const float*)d_in[6];
    const float* a1   = (const float*)d_in[7];
    const float* W2   = (const float*)d_in[8];
    const float* b2   = (const float*)d_in[9];
    const float* a2   = (const float*)d_in[10];

    float* out  = (float*)d_out;
    float* pred = out;                 // 100000
    float* var  = out + NB * NR;       // 10000
    float* sig  = out + NB * NR + NB;  // 10

    float* emb  = (float*)d_ws;        // N_PTS*DOUT floats (4 MB)
    float* part = emb + (size_t)N_PTS * DOUT; // NB*NR floats (400 KB)

    mlp_kernel<<<(N_PTS + 255) / 256, 256, 0, stream>>>(x, W1, b1, a1, W2, b2, a2, emb);
    solve_kernel<<<NB / 2, 128, 0, stream>>>(emb, bidx, bnn, tnn, pred, var, part);
    reduce_kernel<<<1, 256, 0, stream>>>(part, sig);
}

// Round 14
// 187.350 us; speedup vs baseline: 1.5235x; 1.0630x over previous
//
#include <hip/hip_runtime.h>
#include <cstdint>

// Problem constants (match reference)
#define N_PTS 100000
#define DIN   40
#define DH    30
#define DOUT  10
#define NB    10000
#define NNB   64
#define NR    10
#define EPSF  1e-5f

// v_rcp_f32 + one Newton step: ~fp32-exact (R6: raw rcp on pivots -> 8x
// worse absmax).
__device__ __forceinline__ float rcp_nr(float x) {
    float r = __builtin_amdgcn_rcpf(x);
    return r * (2.0f - x * r);
}

// Raw v_sqrt_f32 (no libm fixup; args in [0, ~200]).
__device__ __forceinline__ float fast_sqrt(float x) {
    return __builtin_amdgcn_sqrtf(x);
}

// Broadcast lane LANE's value via v_readlane_b32 -> SGPR (VALU pipe, not the
// per-CU DS crossbar: R3 lesson).
//
// NUMERICS INVARIANT (R12 lesson -- DO NOT BREAK): ~200 of the 10k batches
// contain exactly-duplicated neighbor indices. For those, dj (dot chain)
// must be BITWISE EQUAL to sq (norm chain) -> single sequential fma chain
// over d=0..9 in Build. Elimination ORDER of independent elements is free;
// the per-element BUILD arithmetic is not.
__device__ __forceinline__ float lane_bcast(float x, int lane) {
    return __int_as_float(__builtin_amdgcn_readlane(__float_as_int(x), lane));
}

// R14: rank-1 update with EXPLICIT arch-VGPR constraint. R13's counters show
// ~15.5k issued VALU-cyc-equivalents per wave vs ~8.1k source instrs with
// VGPR_Count=60: the allocator AGPR-parks ar[] (its choice at every
// launch-bounds setting, R4-R9) and v_readlane can't source AGPRs -> one
// v_accvgpr_read per broadcast. "+v" on the element at EVERY use removes the
// allocator's incentive to park it. v_fmac_f32 a += s0*s1 with s0=p (SGPR,
// the 1 allowed scalar operand) and s1=negm (VGPR, divergent) is bit-
// identical to fmaf(-m, p, a).
__device__ __forceinline__ void fma_arch(float& a, const float negm, const float p) {
    asm("v_fmac_f32 %0, %2, %1" : "+v"(a) : "v"(negm), "s"(p));
}

// ---------------------------------------------------------------------------
// Kernel 1: MLP embedding. One point per thread; weights staged in LDS.
// ---------------------------------------------------------------------------
__global__ __launch_bounds__(256) void mlp_kernel(
    const float* __restrict__ x,
    const float* __restrict__ W1, const float* __restrict__ b1, const float* __restrict__ a1p,
    const float* __restrict__ W2, const float* __restrict__ b2, const float* __restrict__ a2p,
    float* __restrict__ emb)
{
    __shared__ float sW1[DH * DIN];
    __shared__ float sW2[DOUT * DH];
    __shared__ float sb1[DH];
    __shared__ float sb2[DOUT];
    for (int i = threadIdx.x; i < DH * DIN; i += 256) sW1[i] = W1[i];
    for (int i = threadIdx.x; i < DOUT * DH; i += 256) sW2[i] = W2[i];
    if (threadIdx.x < DH)   sb1[threadIdx.x] = b1[threadIdx.x];
    if (threadIdx.x < DOUT) sb2[threadIdx.x] = b2[threadIdx.x];
    const float a1 = a1p[0], a2 = a2p[0];
    __syncthreads();

    const int n = blockIdx.x * 256 + threadIdx.x;
    if (n >= N_PTS) return;

    float xv[DIN];
    const float4* xp = reinterpret_cast<const float4*>(x + (size_t)n * DIN); // 160B rows
#pragma unroll
    for (int q = 0; q < DIN / 4; ++q) {
        float4 v = xp[q];
        xv[4*q+0] = v.x; xv[4*q+1] = v.y; xv[4*q+2] = v.z; xv[4*q+3] = v.w;
    }

    float h[DH];
#pragma unroll
    for (int i = 0; i < DH; ++i) {
        float acc = sb1[i];
#pragma unroll
        for (int j = 0; j < DIN; ++j) acc = fmaf(xv[j], sW1[i * DIN + j], acc);
        h[i] = acc > 0.0f ? acc : a1 * acc;
    }

    float* eo = emb + (size_t)n * DOUT;
#pragma unroll
    for (int d = 0; d < DOUT; ++d) {
        float acc = sb2[d];
#pragma unroll
        for (int i = 0; i < DH; ++i) acc = fmaf(h[i], sW2[d * DH + i], acc);
        eo[d] = acc > 0.0f ? acc : a2 * acc;
    }
}

// ---------------------------------------------------------------------------
// Template-recursive solve blocks: every array index AND readlane lane index
// is a compile-time constant (R2: runtime k -> scratch; R3: __shfl -> DS).
// ---------------------------------------------------------------------------

// Build row `lane` of Kplus = exp(-dist) + eps*I.
// Readlanes batched; dj is a SINGLE sequential fma chain (invariant above).
template<int J>
struct Build {
    static __device__ __forceinline__ void run(float (&ar)[NNB], const float (&xn)[DOUT],
                                               const float sq, const int lane) {
        float px[DOUT];
#pragma unroll
        for (int d = 0; d < DOUT; ++d) px[d] = lane_bcast(xn[d], J);
        float dj = 0.0f;
#pragma unroll
        for (int d = 0; d < DOUT; ++d) dj = fmaf(px[d], xn[d], dj);
        const float sqj = lane_bcast(sq, J);
        const float d2  = sq + sqj - 2.0f * dj;
        const float kij = __expf(-fast_sqrt(fmaxf(d2, 0.0f)));
        ar[J] = (J == lane) ? (1.0f + EPSF) : kij;   // exact diag + jitter
        Build<J + 1>::run(ar, xn, sq, lane);
    }
};
template<>
struct Build<NNB> {
    static __device__ __forceinline__ void run(float (&)[NNB], const float (&)[DOUT],
                                               float, int) {}
};

// Batched rank-1 update group: CNT readlanes, then CNT arch-constrained fmacs.
template<int K, int J, int CNT>
struct Grp {
    static __device__ __forceinline__ void run(float (&ar)[NNB], const float negm) {
        float p[CNT];
#pragma unroll
        for (int t = 0; t < CNT; ++t) p[t] = lane_bcast(ar[J + t], K);
#pragma unroll
        for (int t = 0; t < CNT; ++t) fma_arch(ar[J + t], negm, p[t]);
    }
};

// Drive groups of 8 over the suffix [J, NNB)
template<int K, int J>
struct Suffix {
    static __device__ __forceinline__ void run(float (&ar)[NNB], const float negm) {
        constexpr int REM = NNB - J;
        constexpr int CNT = (REM < 8) ? REM : 8;
        Grp<K, J, CNT>::run(ar, negm);
        if constexpr (J + CNT < NNB) Suffix<K, J + CNT>::run(ar, negm);
    }
};

// Software-pipelined Gauss-Jordan step K (R10/R13 semantics exactly).
template<int K>
struct GJ {
    static __device__ __forceinline__ void run(float (&ar)[NNB], float (&rr)[NR + 1],
                                               float& mydiag, const int lane,
                                               const float inv) {
        const float m    = (lane == K) ? 0.0f : ar[K] * inv;
        const float negm = -m;
        mydiag = (lane == K) ? ar[K] : mydiag;    // column K never touched again

        // Column K+1 first (pivot-row value from lane K, pre-update)
        {
            const float p = lane_bcast(ar[K + 1], K);
            fma_arch(ar[K + 1], negm, p);
        }
        // Next pivot chain launches early: lane K+1's ar[K+1] is now final
        const float inv_next = rcp_nr(lane_bcast(ar[K + 1], K + 1));

        // Bulk updates, batched 8-wide; overlap inv_next's latency
        if constexpr (K + 2 < NNB) Suffix<K, K + 2>::run(ar, negm);

        // RHS: all 11 readlanes, then all 11 constrained fmacs
        {
            float pr[NR + 1];
#pragma unroll
            for (int r = 0; r <= NR; ++r) pr[r] = lane_bcast(rr[r], K);
#pragma unroll
            for (int r = 0; r <= NR; ++r) fma_arch(rr[r], negm, pr[r]);
        }

        GJ<K + 1>::run(ar, rr, mydiag, lane, inv_next);
    }
};
// Last step: only the RHS remains.
template<>
struct GJ<NNB - 1> {
    static __device__ __forceinline__ void run(float (&ar)[NNB], float (&rr)[NR + 1],
                                               float& mydiag, const int lane,
                                               const float inv) {
        constexpr int K  = NNB - 1;
        const float m    = (lane == K) ? 0.0f : ar[K] * inv;
        const float negm = -m;
        mydiag = (lane == K) ? ar[K] : mydiag;
        float pr[NR + 1];
#pragma unroll
        for (int r = 0; r <= NR; ++r) pr[r] = lane_bcast(rr[r], K);
#pragma unroll
        for (int r = 0; r <= NR; ++r) fma_arch(rr[r], negm, pr[r]);
    }
};

// ---------------------------------------------------------------------------
// Kernel 2: one wave per batch item, 2 items per 128-thread block.
// (128, 2): loose cap (256) so the forced ~100-arch allocation fits without
// spills; occupancy follows usage (~2048/110 ≈ 18 waves/CU).
// ---------------------------------------------------------------------------
__global__ __launch_bounds__(128, 2) void solve_kernel(
    const float* __restrict__ emb,
    const int* __restrict__ bidx,
    const int* __restrict__ bnn,
    const float* __restrict__ tnn_g,
    float* __restrict__ pred,   // [NB][NR]
    float* __restrict__ var,    // [NB]
    float* __restrict__ part)   // [NB][NR] sigma_sq partials
{
    const int wave = threadIdx.x >> 6;        // 0..1
    const int lane = threadIdx.x & 63;
    const int b    = blockIdx.x * 2 + wave;   // NB = 5000*2, exact

    // Gather this lane's neighbor embedding (10 floats, 8B-aligned rows)
    const int idx = bnn[b * NNB + lane];
    float xn[DOUT];
    {
        const float2* ep = reinterpret_cast<const float2*>(emb + (size_t)idx * DOUT);
#pragma unroll
        for (int q = 0; q < DOUT / 2; ++q) { float2 v = ep[q]; xn[2*q] = v.x; xn[2*q+1] = v.y; }
    }
    // Center embedding (same for all lanes; broadcast through cache)
    const int bi = bidx[b];
    float sq = 0.0f, dotb = 0.0f, sqb = 0.0f;
#pragma unroll
    for (int d = 0; d < DOUT; ++d) {
        const float xbd = emb[(size_t)bi * DOUT + d];
        sq   = fmaf(xn[d], xn[d], sq);
        dotb = fmaf(xbd, xn[d], dotb);
        sqb  = fmaf(xbd, xbd, sqb);
    }
    const float d2c = sqb + sq - 2.0f * dotb;
    const float kc  = __expf(-fast_sqrt(fmaxf(d2c, 0.0f)));

    // K matrix row (registers, static indices only)
    float ar[NNB];
    Build<0>::run(ar, xn, sq, lane);

    // RHS row: [targets(10), Kcross]. tn reloaded at the end (pressure).
    float rr[NR + 1];
    {
        const float2* tp = reinterpret_cast<const float2*>(
            tnn_g + (size_t)b * NNB * NR + (size_t)lane * NR);
#pragma unroll
        for (int q = 0; q < NR / 2; ++q) { float2 v = tp[q]; rr[2*q] = v.x; rr[2*q+1] = v.y; }
    }
    rr[NR] = kc;

    // Prologue of the pipeline: step-0 pivot chain
    const float inv0 = rcp_nr(lane_bcast(ar[0], 0));
    float mydiag = 1.0f;
    GJ<0>::run(ar, rr, mydiag, lane, inv0);
    const float dinv = rcp_nr(mydiag);   // x_i = rr_i * dinv (A now diagonal)

    // Reload targets for sigma_sq partials
    float tn[NR];
    {
        const float2* tp = reinterpret_cast<const float2*>(
            tnn_g + (size_t)b * NNB * NR + (size_t)lane * NR);
#pragma unroll
        for (int q = 0; q < NR / 2; ++q) { float2 v = tp[q]; tn[2*q] = v.x; tn[2*q+1] = v.y; }
    }

    // Outputs: predictions, variance, sigma_sq partials (wave butterfly reduce)
    float pv[NR], sg[NR];
#pragma unroll
    for (int r = 0; r < NR; ++r) {
        const float xr = rr[r] * dinv;     // coeffs[lane][r]
        pv[r] = kc * xr;
        sg[r] = tn[r] * xr;
    }
    float vv = kc * rr[NR] * dinv;         // kc * kc_solve[lane]
#pragma unroll
    for (int off = 32; off > 0; off >>= 1) {
#pragma unroll
        for (int r = 0; r < NR; ++r) {
            pv[r] += __shfl_xor(pv[r], off);
            sg[r] += __shfl_xor(sg[r], off);
        }
        vv += __shfl_xor(vv, off);
    }
    if (lane == 0) {
#pragma unroll
        for (int r = 0; r < NR; ++r) {
            pred[b * NR + r] = pv[r];
            part[b * NR + r] = sg[r];
        }
        var[b] = 1.0f - vv;
    }
}

// ---------------------------------------------------------------------------
// Kernel 3: deterministic reduction of sigma_sq partials (fixed order)
// ---------------------------------------------------------------------------
__global__ __launch_bounds__(256) void reduce_kernel(
    const float* __restrict__ part, float* __restrict__ sig)
{
    float acc[NR];
#pragma unroll
    for (int r = 0; r < NR; ++r) acc[r] = 0.0f;
    for (int b = threadIdx.x; b < NB; b += 256) {
#pragma unroll
        for (int r = 0; r < NR; ++r) acc[r] += part[b * NR + r];
    }
#pragma unroll
    for (int off = 32; off > 0; off >>= 1) {
#pragma unroll
        for (int r = 0; r < NR; ++r) acc[r] += __shfl_xor(acc[r], off);
    }
    __shared__ float s[4][NR];
    const int w = threadIdx.x >> 6, l = threadIdx.x & 63;
    if (l == 0) {
#pragma unroll
        for (int r = 0; r < NR; ++r) s[w][r] = acc[r];
    }
    __syncthreads();
    if (threadIdx.x == 0) {
        const float scale = 1.0f / ((float)NB * (float)NNB);
#pragma unroll
        for (int r = 0; r < NR; ++r)
            sig[r] = (s[0][r] + s[1][r] + s[2][r] + s[3][r]) * scale;
    }
}

// ---------------------------------------------------------------------------
extern "C" void kernel_launch(void* const* d_in, const int* in_sizes, int n_in,
                              void* d_out, int out_size, void* d_ws, size_t ws_size,
                              hipStream_t stream)
{
    const float* x    = (const float*)d_in[0];
    const int*   bidx = (const int*)  d_in[1];
    const int*   bnn  = (const int*)  d_in[2];
    // d_in[3] = batch_targets: unused by the reference computation
    const float* tnn  = (const float*)d_in[4];
    const float* W1   = (const float*)d_in[5];
    const float* b1   = (const float*)d_in[6];
    const float* a1   = (const float*)d_in[7];
    const float* W2   = (const float*)d_in[8];
    const float* b2   = (const float*)d_in[9];
    const float* a2   = (const float*)d_in[10];

    float* out  = (float*)d_out;
    float* pred = out;                 // 100000
    float* var  = out + NB * NR;       // 10000
    float* sig  = out + NB * NR + NB;  // 10

    float* emb  = (float*)d_ws;        // N_PTS*DOUT floats (4 MB)
    float* part = emb + (size_t)N_PTS * DOUT; // NB*NR floats (400 KB)

    mlp_kernel<<<(N_PTS + 255) / 256, 256, 0, stream>>>(x, W1, b1, a1, W2, b2, a2, emb);
    solve_kernel<<<NB / 2, 128, 0, stream>>>(emb, bidx, bnn, tnn, pred, var, part);
    reduce_kernel<<<1, 256, 0, stream>>>(part, sig);
}